// Round 3
// baseline (7791.773 us; speedup 1.0000x reference)
//
#include <hip/hip_runtime.h>

typedef unsigned short u16;
typedef __attribute__((ext_vector_type(4))) float f32x4;
typedef __attribute__((ext_vector_type(8))) __bf16 bf16x8;

#define DM 768
#define NHD 12
#define HD 64
#define NT 171
#define NB 64
#define MREAL (NB*NT)      /* 10944 */
#define MPAD 11008
#define MCONV (NB*170)     /* 10880 */
#define KCONV 608

__device__ __forceinline__ float bf2f(u16 v) {
    union { unsigned int u; float f; } c; c.u = ((unsigned int)v) << 16; return c.f;
}
__device__ __forceinline__ u16 f2bf(float f) {
    union { float f; unsigned int u; } c; c.f = f;
    unsigned int u = c.u;
    u += 0x7fffu + ((u >> 16) & 1u);
    return (u16)(u >> 16);
}

typedef __attribute__((address_space(1))) void GV;
typedef __attribute__((address_space(3))) void LV;
__device__ __forceinline__ void gld_lds16(const u16* g, u16* l) {
    __builtin_amdgcn_global_load_lds((GV*)g, (LV*)l, 16, 0, 0);
}

// ---------------------------------------------------------------- GEMM (NT)
// C[M,N] = A[M,K] * Bt[N,K]^T ; A,Bt bf16 row-major, K % 32 == 0.
#define EPI_F32  0
#define EPI_BF16 1
#define EPI_GELU 2
#define EPI_RES  3

template<int EPI>
__global__ __launch_bounds__(256)
void gemm_nt(const u16* __restrict__ A, const u16* __restrict__ Bt,
             const float* __restrict__ bias,
             float* __restrict__ outF, u16* __restrict__ outB,
             int M, int N, int K, int Mstore)
{
    __shared__ __align__(16) u16 As[128 * 32];
    __shared__ __align__(16) u16 Bs[128 * 32];
    const int tid  = threadIdx.x;
    const int lane = tid & 63;
    const int wave = tid >> 6;
    const int wm = wave >> 1, wn = wave & 1;
    const int m0 = blockIdx.y * 128;
    const int n0 = blockIdx.x * 128;

    f32x4 acc[4][4];
#pragma unroll
    for (int i = 0; i < 4; ++i)
#pragma unroll
        for (int j = 0; j < 4; ++j)
            acc[i][j] = (f32x4){0.f, 0.f, 0.f, 0.f};

    const int r_lo = lane & 15;
    const int kg   = lane >> 4;
    const int swz  = (r_lo >> 1) & 3;

    for (int kt = 0; kt < K; kt += 32) {
        __syncthreads();
#pragma unroll
        for (int i = 0; i < 2; ++i) {
            const int idx = i * 256 + tid;          // 0..511 chunk id (16B chunks)
            const int row = idx >> 2;
            const int cp  = idx & 3;
            const int cg  = cp ^ ((row >> 1) & 3);  // inverse-swizzled global source
            gld_lds16(A  + (size_t)(m0 + row) * K + kt + cg * 8, As + idx * 8);
            gld_lds16(Bt + (size_t)(n0 + row) * K + kt + cg * 8, Bs + idx * 8);
        }
        __syncthreads();

        bf16x8 a[4], b[4];
#pragma unroll
        for (int mi = 0; mi < 4; ++mi) {
            const int row = wm * 64 + mi * 16 + r_lo;
            a[mi] = *(const bf16x8*)(As + row * 32 + (kg ^ swz) * 8);
        }
#pragma unroll
        for (int ni = 0; ni < 4; ++ni) {
            const int row = wn * 64 + ni * 16 + r_lo;
            b[ni] = *(const bf16x8*)(Bs + row * 32 + (kg ^ swz) * 8);
        }
#pragma unroll
        for (int mi = 0; mi < 4; ++mi)
#pragma unroll
            for (int ni = 0; ni < 4; ++ni)
                acc[mi][ni] = __builtin_amdgcn_mfma_f32_16x16x32_bf16(a[mi], b[ni], acc[mi][ni], 0, 0, 0);
    }

    const int erow = (lane >> 4) * 4;
    const int ecol = lane & 15;
#pragma unroll
    for (int mi = 0; mi < 4; ++mi)
#pragma unroll
        for (int ni = 0; ni < 4; ++ni)
#pragma unroll
            for (int rr = 0; rr < 4; ++rr) {
                const int row = m0 + wm * 64 + mi * 16 + erow + rr;
                const int col = n0 + wn * 64 + ni * 16 + ecol;
                if (row < Mstore) {
                    float v = acc[mi][ni][rr];
                    if constexpr (EPI == EPI_F32) {
                        outF[(size_t)row * N + col] = v;
                    } else if constexpr (EPI == EPI_BF16) {
                        v += bias[col];
                        outB[(size_t)row * N + col] = f2bf(v);
                    } else if constexpr (EPI == EPI_GELU) {
                        v += bias[col];
                        v = 0.5f * v * (1.f + erff(v * 0.70710678118f));
                        outB[(size_t)row * N + col] = f2bf(v);
                    } else {
                        v += bias[col];
                        outF[(size_t)row * N + col] += v;
                    }
                }
            }
}

// -------------------------------------------------- weight transpose->bf16
// in: [K,N] f32, out: [N,K] bf16. K,N multiples of 32.
__global__ void transpose_to_bf16(const float* __restrict__ in, u16* __restrict__ out,
                                  int K, int N)
{
    __shared__ float tile[32][33];
    const int kb = blockIdx.y * 32, nb = blockIdx.x * 32;
    const int tx = threadIdx.x, ty = threadIdx.y;
#pragma unroll
    for (int i = 0; i < 32; i += 8)
        tile[ty + i][tx] = in[(size_t)(kb + ty + i) * N + nb + tx];
    __syncthreads();
#pragma unroll
    for (int i = 0; i < 32; i += 8)
        out[(size_t)(nb + ty + i) * K + kb + tx] = f2bf(tile[tx][ty + i]);
}

// conv_w [768,600] f32 -> [768,608] bf16 (zero-pad cols)
__global__ void convw_kernel(const float* __restrict__ in, u16* __restrict__ out)
{
    const int idx = blockIdx.x * 256 + threadIdx.x;
    if (idx >= 768 * KCONV) return;
    const int c = idx / KCONV, t = idx - c * KCONV;
    out[idx] = (t < 600) ? f2bf(in[c * 600 + t]) : (u16)0;
}

// im2col: x[64,6,50,345] -> A[10880][608] bf16
__global__ void im2col_kernel(const float* __restrict__ x, u16* __restrict__ out)
{
    const int idx = blockIdx.x * 256 + threadIdx.x;
    if (idx >= MCONV * KCONV) return;
    const int m = idx / KCONV, t = idx - m * KCONV;
    u16 v = 0;
    if (t < 600) {
        const int ci = t / 100, rem = t - ci * 100;
        const int rr = rem / 10, ww = rem - rr * 10;
        const int b = m / 170, pp = m - b * 170;
        const int ph = pp / 34, pw = pp - ph * 34;
        v = f2bf(x[(((size_t)b * 6 + ci) * 50 + ph * 10 + rr) * 345 + pw * 10 + ww]);
    }
    out[idx] = v;
}

// h[b*171+t][c]: t==0 -> cls+pos ; else conv_out + conv_b + pos
__global__ void assemble_kernel(const float* __restrict__ conv_out, const float* __restrict__ conv_b,
                                const float* __restrict__ cls, const float* __restrict__ pos,
                                float* __restrict__ h)
{
    const int idx = blockIdx.x * 256 + threadIdx.x;
    if (idx >= MREAL * DM) return;
    const int row = idx / DM, c = idx - row * DM;
    const int b = row / NT, t = row - b * NT;
    float v;
    if (t == 0) v = cls[c] + pos[c];
    else v = conv_out[((size_t)b * 170 + (t - 1)) * DM + c] + conv_b[c] + pos[(size_t)t * DM + c];
    h[idx] = v;
}

// LayerNorm over 768; one block per row. outb!=null -> bf16 out, else f32 out.
__global__ __launch_bounds__(256)
void ln_kernel(const float* __restrict__ in, long istride,
               const float* __restrict__ w, const float* __restrict__ bb,
               u16* __restrict__ outb, float* __restrict__ outf, long ostride)
{
    const int row = blockIdx.x;
    const float* xr = in + (size_t)row * istride;
    const int tid = threadIdx.x;
    const float x0 = xr[tid], x1 = xr[tid + 256], x2 = xr[tid + 512];
    float s = x0 + x1 + x2;
    float q = x0 * x0 + x1 * x1 + x2 * x2;
#pragma unroll
    for (int off = 32; off > 0; off >>= 1) {
        s += __shfl_down(s, off);
        q += __shfl_down(q, off);
    }
    __shared__ float ss[4], qq[4];
    if ((tid & 63) == 0) { ss[tid >> 6] = s; qq[tid >> 6] = q; }
    __syncthreads();
    const float ts = ss[0] + ss[1] + ss[2] + ss[3];
    const float tq = qq[0] + qq[1] + qq[2] + qq[3];
    const float mean = ts * (1.0f / 768.0f);
    const float var  = tq * (1.0f / 768.0f) - mean * mean;
    const float inv  = rsqrtf(var + 1e-5f);
    const float xs[3] = {x0, x1, x2};
#pragma unroll
    for (int i = 0; i < 3; ++i) {
        const int c = tid + i * 256;
        const float v = (xs[i] - mean) * inv * w[c] + bb[c];
        if (outb) outb[(size_t)row * ostride + c] = f2bf(v);
        else      outf[(size_t)row * ostride + c] = v;
    }
}

// Attention: one block per (b, head). qkv bf16 [rows 2304], o bf16 [rows 768].
__global__ __launch_bounds__(256)
void attn_kernel(const u16* __restrict__ qkv, u16* __restrict__ o)
{
    const int bh = blockIdx.x;
    const int b = bh / NHD, hh = bh - b * NHD;
    __shared__ __align__(16) u16 ks[NT * 68];
    __shared__ __align__(16) u16 vs[NT * 64];
    __shared__ __align__(16) float qs[16 * 64];
    __shared__ float Ss[16 * 172];
    const int tid = threadIdx.x;
    const u16* base = qkv + (size_t)b * NT * 2304 + hh * HD;

    for (int c = tid; c < NT * 16; c += 256) {
        const int kp = c >> 4, dc = c & 15;
        const u16* krow = base + (size_t)kp * 2304;
        *(ushort4*)&ks[kp * 68 + dc * 4] = *(const ushort4*)(krow + 768 + dc * 4);
        *(ushort4*)&vs[kp * 64 + dc * 4] = *(const ushort4*)(krow + 1536 + dc * 4);
    }
    const int r = tid >> 4, cc = tid & 15;
    __syncthreads();

    for (int qt = 0; qt < 11; ++qt) {
        const int qbase = qt * 16;
        const int qn = (NT - qbase < 16) ? (NT - qbase) : 16;
        if (r < qn) {
            const u16* qrow = base + (size_t)(qbase + r) * 2304;
            const ushort4 qv = *(const ushort4*)(qrow + cc * 4);
            qs[r * 64 + cc * 4 + 0] = bf2f(qv.x);
            qs[r * 64 + cc * 4 + 1] = bf2f(qv.y);
            qs[r * 64 + cc * 4 + 2] = bf2f(qv.z);
            qs[r * 64 + cc * 4 + 3] = bf2f(qv.w);
        }
        __syncthreads();
        for (int kp = cc; kp < NT; kp += 16) {
            float a = 0.f;
#pragma unroll
            for (int d4 = 0; d4 < 16; ++d4) {
                const float4  q4 = *(const float4*)&qs[r * 64 + d4 * 4];
                const ushort4 k4 = *(const ushort4*)&ks[kp * 68 + d4 * 4];
                a += q4.x * bf2f(k4.x) + q4.y * bf2f(k4.y) + q4.z * bf2f(k4.z) + q4.w * bf2f(k4.w);
            }
            Ss[r * 172 + kp] = a * 0.125f;
        }
        // row r is owned by one 16-lane group of one wave: no cross-wave hazard
        float mx = -1e30f;
        for (int kp = cc; kp < NT; kp += 16) mx = fmaxf(mx, Ss[r * 172 + kp]);
#pragma unroll
        for (int off = 8; off > 0; off >>= 1) mx = fmaxf(mx, __shfl_xor(mx, off, 16));
        float sum = 0.f;
        for (int kp = cc; kp < NT; kp += 16) {
            const float e = __expf(Ss[r * 172 + kp] - mx);
            Ss[r * 172 + kp] = e;
            sum += e;
        }
#pragma unroll
        for (int off = 8; off > 0; off >>= 1) sum += __shfl_xor(sum, off, 16);
        const float inv = 1.0f / sum;

        float a0 = 0.f, a1 = 0.f, a2 = 0.f, a3 = 0.f;
        for (int kp = 0; kp < NT; ++kp) {
            const float p = Ss[r * 172 + kp];
            const ushort4 v4 = *(const ushort4*)&vs[kp * 64 + cc * 4];
            a0 = fmaf(p, bf2f(v4.x), a0);
            a1 = fmaf(p, bf2f(v4.y), a1);
            a2 = fmaf(p, bf2f(v4.z), a2);
            a3 = fmaf(p, bf2f(v4.w), a3);
        }
        if (r < qn) {
            u16* orow = o + (size_t)(b * NT + qbase + r) * DM + hh * HD + cc * 4;
            orow[0] = f2bf(a0 * inv);
            orow[1] = f2bf(a1 * inv);
            orow[2] = f2bf(a2 * inv);
            orow[3] = f2bf(a3 * inv);
        }
        __syncthreads();
    }
}

// head: out[b,j] = cls_y[b,:] . head_w[:,j] + head_b[j]
__global__ void head_kernel(const float* __restrict__ cls, const float* __restrict__ hw,
                            const float* __restrict__ hb, float* __restrict__ out)
{
    const int b = blockIdx.x, lane = threadIdx.x;
    float a0 = 0.f, a1 = 0.f, a2 = 0.f;
    for (int d = lane; d < 768; d += 64) {
        const float v = cls[(size_t)b * 768 + d];
        a0 = fmaf(v, hw[d * 3 + 0], a0);
        a1 = fmaf(v, hw[d * 3 + 1], a1);
        a2 = fmaf(v, hw[d * 3 + 2], a2);
    }
#pragma unroll
    for (int off = 32; off > 0; off >>= 1) {
        a0 += __shfl_down(a0, off);
        a1 += __shfl_down(a1, off);
        a2 += __shfl_down(a2, off);
    }
    if (lane == 0) {
        out[b * 3 + 0] = a0 + hb[0];
        out[b * 3 + 1] = a1 + hb[1];
        out[b * 3 + 2] = a2 + hb[2];
    }
}

extern "C" void kernel_launch(void* const* d_in, const int* in_sizes, int n_in,
                              void* d_out, int out_size, void* d_ws, size_t ws_size,
                              hipStream_t stream)
{
    const float* x      = (const float*)d_in[0];
    const float* conv_w = (const float*)d_in[1];
    const float* conv_b = (const float*)d_in[2];
    const float* cls_t  = (const float*)d_in[3];
    const float* pos    = (const float*)d_in[4];
    const float* ln1_w  = (const float*)d_in[5];
    const float* ln1_b  = (const float*)d_in[6];
    const float* qkv_w  = (const float*)d_in[7];
    const float* qkv_b  = (const float*)d_in[8];
    const float* proj_w = (const float*)d_in[9];
    const float* proj_b = (const float*)d_in[10];
    const float* ln2_w  = (const float*)d_in[11];
    const float* ln2_b  = (const float*)d_in[12];
    const float* fc1_w  = (const float*)d_in[13];
    const float* fc1_b  = (const float*)d_in[14];
    const float* fc2_w  = (const float*)d_in[15];
    const float* fc2_b  = (const float*)d_in[16];
    const float* norm_w = (const float*)d_in[17];
    const float* norm_b = (const float*)d_in[18];
    const float* head_w = (const float*)d_in[19];
    const float* head_b = (const float*)d_in[20];

    char* p = (char*)d_ws;
    auto alloc = [&](size_t bytes) { char* r = p; p += (bytes + 255) & ~(size_t)255; return r; };
    float* h    = (float*)alloc((size_t)MPAD * DM * 4);
    u16*   y    = (u16*)  alloc((size_t)MPAD * DM * 2);          // LN out / attn out (reused)
    char*  U    =          alloc((size_t)MPAD * 3072 * 2);       // qkv | mlp | conv scratch (union)
    u16*   Wq   = (u16*)  alloc((size_t)(2304 + 768 + 3072 + 3072) * 768 * 2);
    float* clsy = (float*)alloc((size_t)64 * DM * 4);

    u16*   qkvb = (u16*)U;
    u16*   mlp  = (u16*)U;
    u16*   Ac   = (u16*)U;
    float* conv_out = (float*)(U + (size_t)MCONV * KCONV * 2);
    u16*   Wc = Wq;                       // conv weight bf16 (dead before layer 0)
    u16*   Wp = Wq + (size_t)2304 * 768;
    u16*   W1 = Wp + (size_t)768 * 768;
    u16*   W2 = W1 + (size_t)3072 * 768;

    const dim3 tb(32, 8);

    // ---- patch embedding
    convw_kernel <<<(768 * KCONV) / 256, 256, 0, stream>>>(conv_w, Wc);
    im2col_kernel<<<(MCONV * KCONV) / 256, 256, 0, stream>>>(x, Ac);
    gemm_nt<EPI_F32><<<dim3(6, 85), 256, 0, stream>>>(Ac, Wc, nullptr, conv_out, nullptr,
                                                      MCONV, DM, KCONV, MCONV);
    assemble_kernel<<<(MREAL * DM + 255) / 256, 256, 0, stream>>>(conv_out, conv_b, cls_t, pos, h);

    // ---- transformer layers
    for (int L = 0; L < 12; ++L) {
        transpose_to_bf16<<<dim3(2304 / 32, 768 / 32), tb, 0, stream>>>(qkv_w + (size_t)L * 768 * 2304, Wq, 768, 2304);
        transpose_to_bf16<<<dim3(768 / 32, 768 / 32),  tb, 0, stream>>>(proj_w + (size_t)L * 768 * 768,  Wp, 768, 768);
        transpose_to_bf16<<<dim3(3072 / 32, 768 / 32), tb, 0, stream>>>(fc1_w + (size_t)L * 768 * 3072, W1, 768, 3072);
        transpose_to_bf16<<<dim3(768 / 32, 3072 / 32), tb, 0, stream>>>(fc2_w + (size_t)L * 3072 * 768, W2, 3072, 768);

        ln_kernel<<<MREAL, 256, 0, stream>>>(h, DM, ln1_w + L * DM, ln1_b + L * DM, y, nullptr, DM);
        gemm_nt<EPI_BF16><<<dim3(18, 86), 256, 0, stream>>>(y, Wq, qkv_b + (size_t)L * 2304,
                                                            nullptr, qkvb, MREAL, 2304, 768, MREAL);
        attn_kernel<<<NB * NHD, 256, 0, stream>>>(qkvb, y);
        gemm_nt<EPI_RES><<<dim3(6, 86), 256, 0, stream>>>(y, Wp, proj_b + (size_t)L * DM,
                                                          h, nullptr, MREAL, DM, 768, MREAL);
        ln_kernel<<<MREAL, 256, 0, stream>>>(h, DM, ln2_w + L * DM, ln2_b + L * DM, y, nullptr, DM);
        gemm_nt<EPI_GELU><<<dim3(24, 86), 256, 0, stream>>>(y, W1, fc1_b + (size_t)L * 3072,
                                                            nullptr, mlp, MREAL, 3072, 768, MREAL);
        gemm_nt<EPI_RES><<<dim3(6, 86), 256, 0, stream>>>(mlp, W2, fc2_b + (size_t)L * DM,
                                                          h, nullptr, MREAL, DM, 3072, MREAL);
    }

    // ---- final LN on CLS rows + head
    ln_kernel<<<64, 256, 0, stream>>>(h, (long)NT * DM, norm_w, norm_b, nullptr, clsy, DM);
    head_kernel<<<64, 64, 0, stream>>>(clsy, head_w, head_b, (float*)d_out);
}

// Round 4
// 5775.476 us; speedup vs baseline: 1.3491x; 1.3491x over previous
//
#include <hip/hip_runtime.h>

typedef unsigned short u16;
typedef __attribute__((ext_vector_type(4))) float f32x4;
typedef __attribute__((ext_vector_type(8))) __bf16 bf16x8;

#define DM 768
#define NHD 12
#define HD 64
#define NT 171
#define NB 64
#define MREAL (NB*NT)      /* 10944 */
#define MPAD 11008
#define MCONV (NB*170)     /* 10880 */
#define KCONV 608

__device__ __forceinline__ float bf2f(u16 v) {
    union { unsigned int u; float f; } c; c.u = ((unsigned int)v) << 16; return c.f;
}
__device__ __forceinline__ u16 f2bf(float f) {
    union { float f; unsigned int u; } c; c.f = f;
    unsigned int u = c.u;
    u += 0x7fffu + ((u >> 16) & 1u);
    return (u16)(u >> 16);
}

typedef __attribute__((address_space(1))) void GV;
typedef __attribute__((address_space(3))) void LV;
__device__ __forceinline__ void gld_lds16(const u16* g, u16* l) {
    __builtin_amdgcn_global_load_lds((GV*)g, (LV*)l, 16, 0, 0);
}

// ---------------------------------------------------------------- GEMM (NT)
// C[M,N] = A[M,K] * Bt[N,K]^T ; A,Bt bf16 row-major, K % 32 == 0.
#define EPI_F32  0
#define EPI_BF16 1
#define EPI_GELU 2
#define EPI_RES  3

template<int EPI>
__global__ __launch_bounds__(256)
void gemm_nt(const u16* __restrict__ A, const u16* __restrict__ Bt,
             const float* __restrict__ bias,
             float* __restrict__ outF, u16* __restrict__ outB,
             int M, int N, int K, int Mstore)
{
    __shared__ __align__(16) u16 As[128 * 32];
    __shared__ __align__(16) u16 Bs[128 * 32];
    const int tid  = threadIdx.x;
    const int lane = tid & 63;
    const int wave = tid >> 6;
    const int wm = wave >> 1, wn = wave & 1;
    const int m0 = blockIdx.y * 128;
    const int n0 = blockIdx.x * 128;

    f32x4 acc[4][4];
#pragma unroll
    for (int i = 0; i < 4; ++i)
#pragma unroll
        for (int j = 0; j < 4; ++j)
            acc[i][j] = (f32x4){0.f, 0.f, 0.f, 0.f};

    const int r_lo = lane & 15;
    const int kg   = lane >> 4;
    const int swz  = (r_lo >> 1) & 3;

    for (int kt = 0; kt < K; kt += 32) {
        __syncthreads();
#pragma unroll
        for (int i = 0; i < 2; ++i) {
            const int idx = i * 256 + tid;          // 0..511 chunk id (16B chunks)
            const int row = idx >> 2;
            const int cp  = idx & 3;
            const int cg  = cp ^ ((row >> 1) & 3);  // inverse-swizzled global source
            gld_lds16(A  + (size_t)(m0 + row) * K + kt + cg * 8, As + idx * 8);
            gld_lds16(Bt + (size_t)(n0 + row) * K + kt + cg * 8, Bs + idx * 8);
        }
        __syncthreads();

        bf16x8 a[4], b[4];
#pragma unroll
        for (int mi = 0; mi < 4; ++mi) {
            const int row = wm * 64 + mi * 16 + r_lo;
            a[mi] = *(const bf16x8*)(As + row * 32 + (kg ^ swz) * 8);
        }
#pragma unroll
        for (int ni = 0; ni < 4; ++ni) {
            const int row = wn * 64 + ni * 16 + r_lo;
            b[ni] = *(const bf16x8*)(Bs + row * 32 + (kg ^ swz) * 8);
        }
#pragma unroll
        for (int mi = 0; mi < 4; ++mi)
#pragma unroll
            for (int ni = 0; ni < 4; ++ni)
                acc[mi][ni] = __builtin_amdgcn_mfma_f32_16x16x32_bf16(a[mi], b[ni], acc[mi][ni], 0, 0, 0);
    }

    const int erow = (lane >> 4) * 4;
    const int ecol = lane & 15;
#pragma unroll
    for (int mi = 0; mi < 4; ++mi)
#pragma unroll
        for (int ni = 0; ni < 4; ++ni)
#pragma unroll
            for (int rr = 0; rr < 4; ++rr) {
                const int row = m0 + wm * 64 + mi * 16 + erow + rr;
                const int col = n0 + wn * 64 + ni * 16 + ecol;
                if (row < Mstore) {
                    float v = acc[mi][ni][rr];
                    if constexpr (EPI == EPI_F32) {
                        outF[(size_t)row * N + col] = v;
                    } else if constexpr (EPI == EPI_BF16) {
                        v += bias[col];
                        outB[(size_t)row * N + col] = f2bf(v);
                    } else if constexpr (EPI == EPI_GELU) {
                        v += bias[col];
                        v = 0.5f * v * (1.f + erff(v * 0.70710678118f));
                        outB[(size_t)row * N + col] = f2bf(v);
                    } else {
                        v += bias[col];
                        outF[(size_t)row * N + col] += v;
                    }
                }
            }
}

// -------------------------------------------------- weight transpose->bf16
// in: [K,N] f32, out: [N,K] bf16. K,N multiples of 32.
__global__ void transpose_to_bf16(const float* __restrict__ in, u16* __restrict__ out,
                                  int K, int N)
{
    __shared__ float tile[32][33];
    const int kb = blockIdx.y * 32, nb = blockIdx.x * 32;
    const int tx = threadIdx.x, ty = threadIdx.y;
#pragma unroll
    for (int i = 0; i < 32; i += 8)
        tile[ty + i][tx] = in[(size_t)(kb + ty + i) * N + nb + tx];
    __syncthreads();
#pragma unroll
    for (int i = 0; i < 32; i += 8)
        out[(size_t)(nb + ty + i) * K + kb + tx] = f2bf(tile[tx][ty + i]);
}

// conv_w [768,600] f32 -> [768,608] bf16 (zero-pad cols)
__global__ void convw_kernel(const float* __restrict__ in, u16* __restrict__ out)
{
    const int idx = blockIdx.x * 256 + threadIdx.x;
    if (idx >= 768 * KCONV) return;
    const int c = idx / KCONV, t = idx - c * KCONV;
    out[idx] = (t < 600) ? f2bf(in[c * 600 + t]) : (u16)0;
}

// im2col: x[64,6,50,345] -> A[10880][608] bf16
__global__ void im2col_kernel(const float* __restrict__ x, u16* __restrict__ out)
{
    const int idx = blockIdx.x * 256 + threadIdx.x;
    if (idx >= MCONV * KCONV) return;
    const int m = idx / KCONV, t = idx - m * KCONV;
    u16 v = 0;
    if (t < 600) {
        const int ci = t / 100, rem = t - ci * 100;
        const int rr = rem / 10, ww = rem - rr * 10;
        const int b = m / 170, pp = m - b * 170;
        const int ph = pp / 34, pw = pp - ph * 34;
        v = f2bf(x[(((size_t)b * 6 + ci) * 50 + ph * 10 + rr) * 345 + pw * 10 + ww]);
    }
    out[idx] = v;
}

// h[b*171+t][c]: t==0 -> cls+pos ; else conv_out + conv_b + pos
__global__ void assemble_kernel(const float* __restrict__ conv_out, const float* __restrict__ conv_b,
                                const float* __restrict__ cls, const float* __restrict__ pos,
                                float* __restrict__ h)
{
    const int idx = blockIdx.x * 256 + threadIdx.x;
    if (idx >= MREAL * DM) return;
    const int row = idx / DM, c = idx - row * DM;
    const int b = row / NT, t = row - b * NT;
    float v;
    if (t == 0) v = cls[c] + pos[c];
    else v = conv_out[((size_t)b * 170 + (t - 1)) * DM + c] + conv_b[c] + pos[(size_t)t * DM + c];
    h[idx] = v;
}

// LayerNorm over 768; one block per row. outb!=null -> bf16 out, else f32 out.
__global__ __launch_bounds__(256)
void ln_kernel(const float* __restrict__ in, long istride,
               const float* __restrict__ w, const float* __restrict__ bb,
               u16* __restrict__ outb, float* __restrict__ outf, long ostride)
{
    const int row = blockIdx.x;
    const float* xr = in + (size_t)row * istride;
    const int tid = threadIdx.x;
    const float x0 = xr[tid], x1 = xr[tid + 256], x2 = xr[tid + 512];
    float s = x0 + x1 + x2;
    float q = x0 * x0 + x1 * x1 + x2 * x2;
#pragma unroll
    for (int off = 32; off > 0; off >>= 1) {
        s += __shfl_down(s, off);
        q += __shfl_down(q, off);
    }
    __shared__ float ss[4], qq[4];
    if ((tid & 63) == 0) { ss[tid >> 6] = s; qq[tid >> 6] = q; }
    __syncthreads();
    const float ts = ss[0] + ss[1] + ss[2] + ss[3];
    const float tq = qq[0] + qq[1] + qq[2] + qq[3];
    const float mean = ts * (1.0f / 768.0f);
    const float var  = tq * (1.0f / 768.0f) - mean * mean;
    const float inv  = rsqrtf(var + 1e-5f);
    const float xs[3] = {x0, x1, x2};
#pragma unroll
    for (int i = 0; i < 3; ++i) {
        const int c = tid + i * 256;
        const float v = (xs[i] - mean) * inv * w[c] + bb[c];
        if (outb) outb[(size_t)row * ostride + c] = f2bf(v);
        else      outf[(size_t)row * ostride + c] = v;
    }
}

// ---------------------------------------------------------------- Attention
// MFMA flash-style, one block per (b, head). 4 waves.
// QK^T: A/B fragments read DIRECTLY from global (Q,K blocks are L1-resident).
// Softmax fully in-register on the MFMA C-layout (16-lane shfl reduce).
// P staged through per-wave XOR-swizzled LDS; V transpose-staged (swizzled).
__global__ __launch_bounds__(256)
void attn_kernel(const u16* __restrict__ qkv, u16* __restrict__ o)
{
    const int bh = blockIdx.x;
    const int b = bh / NHD, hh = bh - b * NHD;
    // Vt: [64][192] u16 (stride 384B); P: 4 waves x [16][192] u16. 48 KB total.
    __shared__ __align__(16) u16 lds[(64 + 4 * 16) * 192];
    u16* Vt = lds;
    const int tid  = threadIdx.x;
    const int wave = tid >> 6;
    const int lane = tid & 63;
    u16* Pw = lds + 64 * 192 + wave * 16 * 192;

    // zero all of LDS (padded cols of Vt and P must be 0, never NaN)
#pragma unroll
    for (int i = tid * 8; i < 128 * 192; i += 256 * 8)
        *(uint4*)&lds[i] = (uint4){0u, 0u, 0u, 0u};
    __syncthreads();

    const u16* base = qkv + (size_t)b * NT * 2304 + hh * HD;

    // stage V transposed: Vt[d][kp] = V[kp][d], chunk-XOR swizzled by (d&7)
    for (int c = tid; c < NT * 16; c += 256) {
        const int kp = c >> 4, dc = c & 15;
        const ushort4 v4 = *(const ushort4*)(base + (size_t)kp * 2304 + 1536 + dc * 4);
        const u16 vals[4] = {v4.x, v4.y, v4.z, v4.w};
#pragma unroll
        for (int i = 0; i < 4; ++i) {
            const int d = dc * 4 + i;
            const int ch = (kp >> 3) ^ (d & 7);
            Vt[d * 192 + ch * 8 + (kp & 7)] = vals[i];
        }
    }
    __syncthreads();

    const int r_lo = lane & 15;
    const int kg   = lane >> 4;   // also the C-layout row group g

    for (int rt = wave; rt < 11; rt += 4) {
        // ---- QK^T for 16 q-rows [16rt .. 16rt+15], all 176 cols
        const u16* qrow = base + (size_t)(16 * rt + r_lo) * 2304;
        const bf16x8 aq0 = *(const bf16x8*)(qrow + kg * 8);
        const bf16x8 aq1 = *(const bf16x8*)(qrow + 32 + kg * 8);
        f32x4 s[11];
#pragma unroll
        for (int ct = 0; ct < 11; ++ct) s[ct] = (f32x4){0.f, 0.f, 0.f, 0.f};
#pragma unroll
        for (int ct = 0; ct < 11; ++ct) {
            const u16* krow = base + (size_t)(16 * ct + r_lo) * 2304 + 768;
            const bf16x8 bk0 = *(const bf16x8*)(krow + kg * 8);
            const bf16x8 bk1 = *(const bf16x8*)(krow + 32 + kg * 8);
            s[ct] = __builtin_amdgcn_mfma_f32_16x16x32_bf16(aq0, bk0, s[ct], 0, 0, 0);
            s[ct] = __builtin_amdgcn_mfma_f32_16x16x32_bf16(aq1, bk1, s[ct], 0, 0, 0);
        }

        // ---- in-register softmax. lane holds rows 4*kg+r (r=0..3), col l15+16ct
        float mx[4] = {-1e30f, -1e30f, -1e30f, -1e30f};
#pragma unroll
        for (int ct = 0; ct < 11; ++ct)
#pragma unroll
            for (int r = 0; r < 4; ++r) {
                const int col = r_lo + 16 * ct;
                const float v = (col < NT) ? s[ct][r] * 0.125f : -1e30f;
                s[ct][r] = v;
                mx[r] = fmaxf(mx[r], v);
            }
#pragma unroll
        for (int r = 0; r < 4; ++r)
#pragma unroll
            for (int off = 8; off > 0; off >>= 1)
                mx[r] = fmaxf(mx[r], __shfl_xor(mx[r], off, 16));
        float sum[4] = {0.f, 0.f, 0.f, 0.f};
#pragma unroll
        for (int ct = 0; ct < 11; ++ct)
#pragma unroll
            for (int r = 0; r < 4; ++r) {
                const float e = __expf(s[ct][r] - mx[r]);
                s[ct][r] = e;
                sum[r] += e;
            }
#pragma unroll
        for (int r = 0; r < 4; ++r)
#pragma unroll
            for (int off = 8; off > 0; off >>= 1)
                sum[r] += __shfl_xor(sum[r], off, 16);
        const float inv[4] = {1.f / sum[0], 1.f / sum[1], 1.f / sum[2], 1.f / sum[3]};

        // ---- write P (bf16) to per-wave swizzled LDS
#pragma unroll
        for (int ct = 0; ct < 11; ++ct)
#pragma unroll
            for (int r = 0; r < 4; ++r) {
                const int row = 4 * kg + r;
                const int col = r_lo + 16 * ct;
                const int ch = (col >> 3) ^ (row & 7);
                Pw[row * 192 + ch * 8 + (col & 7)] = f2bf(s[ct][r] * inv[r]);
            }

        // ---- PV: O_tile[16 x 64] = P[16 x 192] * V[192 x 64]
        f32x4 oacc[4];
#pragma unroll
        for (int vt = 0; vt < 4; ++vt) oacc[vt] = (f32x4){0.f, 0.f, 0.f, 0.f};
#pragma unroll
        for (int kk = 0; kk < 6; ++kk) {
            const int kc = kk * 4 + kg;               // 16B chunk index 0..23
            const int pch = kc ^ (r_lo & 7);
            const bf16x8 ap = *(const bf16x8*)(Pw + r_lo * 192 + pch * 8);
#pragma unroll
            for (int vt = 0; vt < 4; ++vt) {
                const int vrow = 16 * vt + r_lo;
                const int vch = kc ^ (vrow & 7);
                const bf16x8 bv = *(const bf16x8*)(Vt + vrow * 192 + vch * 8);
                oacc[vt] = __builtin_amdgcn_mfma_f32_16x16x32_bf16(ap, bv, oacc[vt], 0, 0, 0);
            }
        }

        // ---- store O rows < 171
#pragma unroll
        for (int vt = 0; vt < 4; ++vt)
#pragma unroll
            for (int r = 0; r < 4; ++r) {
                const int qr = 16 * rt + 4 * kg + r;
                if (qr < NT)
                    o[(size_t)(b * NT + qr) * DM + hh * HD + 16 * vt + r_lo] = f2bf(oacc[vt][r]);
            }
    }
}

// head: out[b,j] = cls_y[b,:] . head_w[:,j] + head_b[j]
__global__ void head_kernel(const float* __restrict__ cls, const float* __restrict__ hw,
                            const float* __restrict__ hb, float* __restrict__ out)
{
    const int b = blockIdx.x, lane = threadIdx.x;
    float a0 = 0.f, a1 = 0.f, a2 = 0.f;
    for (int d = lane; d < 768; d += 64) {
        const float v = cls[(size_t)b * 768 + d];
        a0 = fmaf(v, hw[d * 3 + 0], a0);
        a1 = fmaf(v, hw[d * 3 + 1], a1);
        a2 = fmaf(v, hw[d * 3 + 2], a2);
    }
#pragma unroll
    for (int off = 32; off > 0; off >>= 1) {
        a0 += __shfl_down(a0, off);
        a1 += __shfl_down(a1, off);
        a2 += __shfl_down(a2, off);
    }
    if (lane == 0) {
        out[b * 3 + 0] = a0 + hb[0];
        out[b * 3 + 1] = a1 + hb[1];
        out[b * 3 + 2] = a2 + hb[2];
    }
}

extern "C" void kernel_launch(void* const* d_in, const int* in_sizes, int n_in,
                              void* d_out, int out_size, void* d_ws, size_t ws_size,
                              hipStream_t stream)
{
    const float* x      = (const float*)d_in[0];
    const float* conv_w = (const float*)d_in[1];
    const float* conv_b = (const float*)d_in[2];
    const float* cls_t  = (const float*)d_in[3];
    const float* pos    = (const float*)d_in[4];
    const float* ln1_w  = (const float*)d_in[5];
    const float* ln1_b  = (const float*)d_in[6];
    const float* qkv_w  = (const float*)d_in[7];
    const float* qkv_b  = (const float*)d_in[8];
    const float* proj_w = (const float*)d_in[9];
    const float* proj_b = (const float*)d_in[10];
    const float* ln2_w  = (const float*)d_in[11];
    const float* ln2_b  = (const float*)d_in[12];
    const float* fc1_w  = (const float*)d_in[13];
    const float* fc1_b  = (const float*)d_in[14];
    const float* fc2_w  = (const float*)d_in[15];
    const float* fc2_b  = (const float*)d_in[16];
    const float* norm_w = (const float*)d_in[17];
    const float* norm_b = (const float*)d_in[18];
    const float* head_w = (const float*)d_in[19];
    const float* head_b = (const float*)d_in[20];

    char* p = (char*)d_ws;
    auto alloc = [&](size_t bytes) { char* r = p; p += (bytes + 255) & ~(size_t)255; return r; };
    float* h    = (float*)alloc((size_t)MPAD * DM * 4);
    u16*   y    = (u16*)  alloc((size_t)MPAD * DM * 2);          // LN out / attn out (reused)
    char*  U    =          alloc((size_t)MPAD * 3072 * 2);       // qkv | mlp | conv scratch (union)
    u16*   Wq   = (u16*)  alloc((size_t)(2304 + 768 + 3072 + 3072) * 768 * 2);
    float* clsy = (float*)alloc((size_t)64 * DM * 4);

    u16*   qkvb = (u16*)U;
    u16*   mlp  = (u16*)U;
    u16*   Ac   = (u16*)U;
    float* conv_out = (float*)(U + (size_t)MCONV * KCONV * 2);
    u16*   Wc = Wq;                       // conv weight bf16 (dead before layer 0)
    u16*   Wp = Wq + (size_t)2304 * 768;
    u16*   W1 = Wp + (size_t)768 * 768;
    u16*   W2 = W1 + (size_t)3072 * 768;

    const dim3 tb(32, 8);

    // ---- patch embedding
    convw_kernel <<<(768 * KCONV) / 256, 256, 0, stream>>>(conv_w, Wc);
    im2col_kernel<<<(MCONV * KCONV) / 256, 256, 0, stream>>>(x, Ac);
    gemm_nt<EPI_F32><<<dim3(6, 85), 256, 0, stream>>>(Ac, Wc, nullptr, conv_out, nullptr,
                                                      MCONV, DM, KCONV, MCONV);
    assemble_kernel<<<(MREAL * DM + 255) / 256, 256, 0, stream>>>(conv_out, conv_b, cls_t, pos, h);

    // ---- transformer layers
    for (int L = 0; L < 12; ++L) {
        transpose_to_bf16<<<dim3(2304 / 32, 768 / 32), tb, 0, stream>>>(qkv_w + (size_t)L * 768 * 2304, Wq, 768, 2304);
        transpose_to_bf16<<<dim3(768 / 32, 768 / 32),  tb, 0, stream>>>(proj_w + (size_t)L * 768 * 768,  Wp, 768, 768);
        transpose_to_bf16<<<dim3(3072 / 32, 768 / 32), tb, 0, stream>>>(fc1_w + (size_t)L * 768 * 3072, W1, 768, 3072);
        transpose_to_bf16<<<dim3(768 / 32, 3072 / 32), tb, 0, stream>>>(fc2_w + (size_t)L * 3072 * 768, W2, 3072, 768);

        ln_kernel<<<MREAL, 256, 0, stream>>>(h, DM, ln1_w + L * DM, ln1_b + L * DM, y, nullptr, DM);
        gemm_nt<EPI_BF16><<<dim3(18, 86), 256, 0, stream>>>(y, Wq, qkv_b + (size_t)L * 2304,
                                                            nullptr, qkvb, MREAL, 2304, 768, MREAL);
        attn_kernel<<<NB * NHD, 256, 0, stream>>>(qkvb, y);
        gemm_nt<EPI_RES><<<dim3(6, 86), 256, 0, stream>>>(y, Wp, proj_b + (size_t)L * DM,
                                                          h, nullptr, MREAL, DM, 768, MREAL);
        ln_kernel<<<MREAL, 256, 0, stream>>>(h, DM, ln2_w + L * DM, ln2_b + L * DM, y, nullptr, DM);
        gemm_nt<EPI_GELU><<<dim3(24, 86), 256, 0, stream>>>(y, W1, fc1_b + (size_t)L * 3072,
                                                            nullptr, mlp, MREAL, 3072, 768, MREAL);
        gemm_nt<EPI_RES><<<dim3(6, 86), 256, 0, stream>>>(mlp, W2, fc2_b + (size_t)L * DM,
                                                          h, nullptr, MREAL, DM, 3072, MREAL);
    }

    // ---- final LN on CLS rows + head
    ln_kernel<<<64, 256, 0, stream>>>(h, (long)NT * DM, norm_w, norm_b, nullptr, clsy, DM);
    head_kernel<<<64, 64, 0, stream>>>(clsy, head_w, head_b, (float*)d_out);
}